// Round 2
// baseline (2140.198 us; speedup 1.0000x reference)
//
#include <hip/hip_runtime.h>
#include <hip/hip_bf16.h>

typedef short bf16x8 __attribute__((ext_vector_type(8)));   // 8 bf16 in 4 VGPRs
typedef float f32x4  __attribute__((ext_vector_type(4)));   // MFMA C/D frag

#define MFMA16(a,b,c) __builtin_amdgcn_mfma_f32_16x16x32_bf16((a),(b),(c),0,0,0)

static constexpr int SEQ = 2048;
static constexpr int DM  = 2048;
static constexpr int NH  = 16;
static constexpr int DH  = 128;
static constexpr int BAT = 4;
static constexpr int BH  = BAT * NH;      // 64
static constexpr int MROWS = BAT * SEQ;   // 8192

// ---------------------------------------------------------------------------
// GEMM: C[m][n] = A[m][:] @ B[:][n] + bias[n].  B is fp32 row-major [K,N],
// converted to bf16 at staging.  64x64 tile / 256 threads, 4 waves 2x2, BK=32.
// MODE 0: A fp32 (convert at staging); epilogue scatters bf16 into the qkv
//         workspace laid out [3][B*H][S][Dh].
// MODE 1: A bf16 (staged directly); epilogue stores fp32 row-major [M,N].
// ---------------------------------------------------------------------------
template<int MODE>
__global__ __launch_bounds__(256)
void gemm64(const void* __restrict__ Aptr, int lda,
            const float* __restrict__ Bm, int ldb,
            const float* __restrict__ bias,
            void* __restrict__ outp, int K)
{
    // +8 pad: row stride 40 elems = 80 B -> <=2-way bank aliasing (free, m136)
    __shared__ __hip_bfloat16 As[64 * 40];
    __shared__ __hip_bfloat16 Bs[64 * 40];   // stored TRANSPOSED: Bs[n][k]

    const int tid  = threadIdx.x;
    const int wave = tid >> 6, lane = tid & 63;
    const int quad = lane >> 4, l16 = lane & 15;
    const int m0 = blockIdx.y * 64, n0 = blockIdx.x * 64;
    const int wm = (wave >> 1) * 32, wn = (wave & 1) * 32;

    f32x4 acc[2][2] = {};

    const int ar = tid >> 2, ac = (tid & 3) * 8;   // A stage: 64 rows x 32 cols
    const int bk = tid >> 3, bn = (tid & 7) * 8;   // B stage: 32 k  x 64 n

    for (int k0 = 0; k0 < K; k0 += 32) {
        // ---- stage A tile ----
        if (MODE == 0) {
            const float* A = (const float*)Aptr;
            const float* ap = A + (size_t)(m0 + ar) * lda + k0 + ac;
            float4 a0 = *(const float4*)(ap);
            float4 a1 = *(const float4*)(ap + 4);
            __hip_bfloat16* dst = &As[ar * 40 + ac];
            dst[0] = __float2bfloat16(a0.x); dst[1] = __float2bfloat16(a0.y);
            dst[2] = __float2bfloat16(a0.z); dst[3] = __float2bfloat16(a0.w);
            dst[4] = __float2bfloat16(a1.x); dst[5] = __float2bfloat16(a1.y);
            dst[6] = __float2bfloat16(a1.z); dst[7] = __float2bfloat16(a1.w);
        } else {
            const __hip_bfloat16* A = (const __hip_bfloat16*)Aptr;
            uint4 av = *(const uint4*)(A + (size_t)(m0 + ar) * lda + k0 + ac);
            *(uint4*)(&As[ar * 40 + ac]) = av;
        }
        // ---- stage B tile transposed (fp32 -> bf16) ----
        {
            const float* bp = Bm + (size_t)(k0 + bk) * ldb + n0 + bn;
            float4 b0 = *(const float4*)(bp);
            float4 b1 = *(const float4*)(bp + 4);
            Bs[(bn + 0) * 40 + bk] = __float2bfloat16(b0.x);
            Bs[(bn + 1) * 40 + bk] = __float2bfloat16(b0.y);
            Bs[(bn + 2) * 40 + bk] = __float2bfloat16(b0.z);
            Bs[(bn + 3) * 40 + bk] = __float2bfloat16(b0.w);
            Bs[(bn + 4) * 40 + bk] = __float2bfloat16(b1.x);
            Bs[(bn + 5) * 40 + bk] = __float2bfloat16(b1.y);
            Bs[(bn + 6) * 40 + bk] = __float2bfloat16(b1.z);
            Bs[(bn + 7) * 40 + bk] = __float2bfloat16(b1.w);
        }
        __syncthreads();

        // fragments: A[m=l16][k=quad*8+j], B[k=quad*8+j][n=l16] (from Bs[n][k])
        bf16x8 a0 = *(const bf16x8*)(&As[(wm      + l16) * 40 + quad * 8]);
        bf16x8 a1 = *(const bf16x8*)(&As[(wm + 16 + l16) * 40 + quad * 8]);
        bf16x8 b0 = *(const bf16x8*)(&Bs[(wn      + l16) * 40 + quad * 8]);
        bf16x8 b1 = *(const bf16x8*)(&Bs[(wn + 16 + l16) * 40 + quad * 8]);
        acc[0][0] = MFMA16(a0, b0, acc[0][0]);
        acc[0][1] = MFMA16(a0, b1, acc[0][1]);
        acc[1][0] = MFMA16(a1, b0, acc[1][0]);
        acc[1][1] = MFMA16(a1, b1, acc[1][1]);
        __syncthreads();
    }

    // epilogue: D row = quad*4+r, col = l16 (verified m89/m91 layout)
    #pragma unroll
    for (int i = 0; i < 2; ++i)
        #pragma unroll
        for (int j = 0; j < 2; ++j)
            #pragma unroll
            for (int r = 0; r < 4; ++r) {
                int row = m0 + wm + i * 16 + quad * 4 + r;
                int col = n0 + wn + j * 16 + l16;
                float v = acc[i][j][r] + bias[col];
                if (MODE == 0) {
                    int which = col >> 11, h = (col >> 7) & 15, d = col & 127;
                    int bb = row >> 11, s = row & 2047;
                    ((__hip_bfloat16*)outp)
                        [(((size_t)which * BH + bb * NH + h) * SEQ + s) * DH + d] =
                        __float2bfloat16(v);
                } else {
                    ((float*)outp)[(size_t)row * DM + col] = v;
                }
            }
}

// ---------------------------------------------------------------------------
// Causal flash attention.  Q/K/V bf16 in [B*H][S][Dh].  One block per
// (q-tile of 64, b*h).  4 waves, each owns 16 q rows.  Online softmax.
// O written bf16 straight into [B][S][D_MODEL] layout for the out-proj GEMM.
// ---------------------------------------------------------------------------
__global__ __launch_bounds__(256)
void attn_kernel(const __hip_bfloat16* __restrict__ q,
                 const __hip_bfloat16* __restrict__ k,
                 const __hip_bfloat16* __restrict__ v,
                 __hip_bfloat16* __restrict__ o)
{
    __shared__ __hip_bfloat16 Qs[64 * 136];   // [qrow][d]  (+8 pad)
    __shared__ __hip_bfloat16 Ks[64 * 136];   // [krow][d]
    __shared__ __hip_bfloat16 Vt[128 * 72];   // TRANSPOSED [d][krow]
    __shared__ __hip_bfloat16 Ps[64 * 72];    // [qrow][krow], wave-private rows

    const int tid  = threadIdx.x;
    const int wave = tid >> 6, lane = tid & 63;
    const int quad = lane >> 4, l16 = lane & 15;
    const int qt = blockIdx.x, bh = blockIdx.y;
    const int q0 = qt * 64;
    const size_t base = (size_t)bh * SEQ * DH;
    const float scale = 0.08838834764831845f;  // 1/sqrt(128)

    // load Q tile once: 64x128 bf16
    #pragma unroll
    for (int it = 0; it < 4; ++it) {
        int e = it * 2048 + tid * 8;
        int row = e >> 7, col = e & 127;
        *(uint4*)(&Qs[row * 136 + col]) =
            *(const uint4*)(q + base + (size_t)(q0 + row) * DH + col);
    }

    float m_run[4], l_run[4];
    f32x4 oacc[8] = {};
    #pragma unroll
    for (int r = 0; r < 4; ++r) { m_run[r] = -1e30f; l_run[r] = 0.f; }

    for (int kt = 0; kt <= qt; ++kt) {
        __syncthreads();   // prior readers of Ks/Vt done (also covers Qs stage)
        // stage K (straight) and V (transposed)
        #pragma unroll
        for (int it = 0; it < 4; ++it) {
            int e = it * 2048 + tid * 8;
            int row = e >> 7, col = e & 127;
            *(uint4*)(&Ks[row * 136 + col]) =
                *(const uint4*)(k + base + (size_t)(kt * 64 + row) * DH + col);
            uint4 vv = *(const uint4*)(v + base + (size_t)(kt * 64 + row) * DH + col);
            const __hip_bfloat16* ve = (const __hip_bfloat16*)&vv;
            #pragma unroll
            for (int j = 0; j < 8; ++j) Vt[(col + j) * 72 + row] = ve[j];
        }
        __syncthreads();

        // S = Q K^T for this wave's 16 q rows x 64 k cols
        f32x4 sacc[4] = {};
        const int arow = wave * 16 + l16;
        #pragma unroll
        for (int kk = 0; kk < 4; ++kk) {
            bf16x8 a = *(const bf16x8*)(&Qs[arow * 136 + kk * 32 + quad * 8]);
            #pragma unroll
            for (int f = 0; f < 4; ++f) {
                bf16x8 b = *(const bf16x8*)(&Ks[(f * 16 + l16) * 136 + kk * 32 + quad * 8]);
                sacc[f] = MFMA16(a, b, sacc[f]);
            }
        }

        // scale + causal mask + online softmax (rows = quad*4+r)
        const int qrow = q0 + wave * 16 + quad * 4;
        float mloc[4] = {-1e30f, -1e30f, -1e30f, -1e30f};
        #pragma unroll
        for (int f = 0; f < 4; ++f)
            #pragma unroll
            for (int r = 0; r < 4; ++r) {
                float s = sacc[f][r] * scale;
                int kg = kt * 64 + f * 16 + l16;
                if (kg > qrow + r) s = -1e30f;
                sacc[f][r] = s;
                mloc[r] = fmaxf(mloc[r], s);
            }
        #pragma unroll
        for (int off = 1; off < 16; off <<= 1)
            #pragma unroll
            for (int r = 0; r < 4; ++r)
                mloc[r] = fmaxf(mloc[r], __shfl_xor(mloc[r], off, 64));

        float alpha[4], lloc[4] = {0.f, 0.f, 0.f, 0.f};
        #pragma unroll
        for (int r = 0; r < 4; ++r) {
            float mn = fmaxf(m_run[r], mloc[r]);
            alpha[r] = __expf(m_run[r] - mn);
            m_run[r] = mn;
        }
        float pv[4][4];
        #pragma unroll
        for (int f = 0; f < 4; ++f)
            #pragma unroll
            for (int r = 0; r < 4; ++r) {
                float pe = __expf(sacc[f][r] - m_run[r]);
                pv[f][r] = pe;
                lloc[r] += pe;
            }
        #pragma unroll
        for (int off = 1; off < 16; off <<= 1)
            #pragma unroll
            for (int r = 0; r < 4; ++r)
                lloc[r] += __shfl_xor(lloc[r], off, 64);
        #pragma unroll
        for (int r = 0; r < 4; ++r) l_run[r] = l_run[r] * alpha[r] + lloc[r];
        #pragma unroll
        for (int dt = 0; dt < 8; ++dt)
            #pragma unroll
            for (int r = 0; r < 4; ++r) oacc[dt][r] *= alpha[r];

        // P (C-layout) -> LDS -> A-layout (verified m120 round-trip)
        #pragma unroll
        for (int f = 0; f < 4; ++f)
            #pragma unroll
            for (int r = 0; r < 4; ++r)
                Ps[(wave * 16 + quad * 4 + r) * 72 + f * 16 + l16] =
                    __float2bfloat16(pv[f][r]);
        __syncthreads();

        // O += P V : P is A (16 x 64), V is B (64 x 128) via Vt[d][s]
        #pragma unroll
        for (int f2 = 0; f2 < 2; ++f2) {
            bf16x8 a = *(const bf16x8*)(&Ps[(wave * 16 + l16) * 72 + f2 * 32 + quad * 8]);
            #pragma unroll
            for (int dt = 0; dt < 8; ++dt) {
                bf16x8 b = *(const bf16x8*)(&Vt[(dt * 16 + l16) * 72 + f2 * 32 + quad * 8]);
                oacc[dt] = MFMA16(a, b, oacc[dt]);
            }
        }
    }

    // epilogue: normalize and store O (bf16) into [B][S][D_MODEL]
    const int bb = bh >> 4, h = bh & 15;
    #pragma unroll
    for (int dt = 0; dt < 8; ++dt)
        #pragma unroll
        for (int r = 0; r < 4; ++r) {
            int srow = q0 + wave * 16 + quad * 4 + r;
            float val = oacc[dt][r] / l_run[r];
            o[((size_t)(bb * SEQ + srow)) * DM + h * DH + dt * 16 + l16] =
                __float2bfloat16(val);
        }
}

// ---------------------------------------------------------------------------
extern "C" void kernel_launch(void* const* d_in, const int* in_sizes, int n_in,
                              void* d_out, int out_size, void* d_ws, size_t ws_size,
                              hipStream_t stream)
{
    const float* x     = (const float*)d_in[0];   // [4,2048,2048] fp32
    const float* w_qkv = (const float*)d_in[1];   // [2048,6144]   fp32
    const float* b_qkv = (const float*)d_in[2];   // [6144]        fp32
    const float* w_out = (const float*)d_in[3];   // [2048,2048]   fp32
    const float* b_out = (const float*)d_in[4];   // [2048]        fp32
    float* out = (float*)d_out;                   // [4,2048,2048] fp32
    __hip_bfloat16* ws = (__hip_bfloat16*)d_ws;

    const size_t t = (size_t)BH * SEQ * DH;    // 16,777,216 elems per tensor
    __hip_bfloat16* qp = ws;                   // bf16 [BH][S][Dh]
    __hip_bfloat16* kp = ws + t;
    __hip_bfloat16* vp = ws + 2 * t;
    __hip_bfloat16* op = ws + 3 * t;           // bf16 [B][S][D] for out-proj

    // 1) fused QKV projection: fp32 [8192,2048] @ [2048,6144] -> bf16 q/k/v
    gemm64<0><<<dim3(3 * DM / 64, MROWS / 64), 256, 0, stream>>>(
        x, DM, w_qkv, 3 * DM, b_qkv, ws, DM);
    // 2) causal flash attention (bf16 in/out, fp32 accumulate)
    attn_kernel<<<dim3(SEQ / 64, BH), 256, 0, stream>>>(qp, kp, vp, op);
    // 3) output projection: bf16 [8192,2048] @ fp32 [2048,2048] -> fp32 d_out
    gemm64<1><<<dim3(DM / 64, MROWS / 64), 256, 0, stream>>>(
        op, DM, w_out, DM, b_out, out, DM);
}

// Round 3
// 939.488 us; speedup vs baseline: 2.2780x; 2.2780x over previous
//
#include <hip/hip_runtime.h>
#include <hip/hip_bf16.h>

typedef short bf16x8 __attribute__((ext_vector_type(8)));   // 8 bf16 in 4 VGPRs
typedef float f32x4  __attribute__((ext_vector_type(4)));   // MFMA C/D frag

#define MFMA16(a,b,c) __builtin_amdgcn_mfma_f32_16x16x32_bf16((a),(b),(c),0,0,0)

typedef __attribute__((address_space(3))) unsigned int       lds_u32;
typedef const __attribute__((address_space(1))) unsigned int g_u32;

static constexpr int SEQ = 2048;
static constexpr int DM  = 2048;
static constexpr int NH  = 16;
static constexpr int DH  = 128;
static constexpr int BAT = 4;
static constexpr int BH  = BAT * NH;      // 64
static constexpr int MROWS = BAT * SEQ;   // 8192

// ---------------------------------------------------------------------------
// fp32 -> bf16 elementwise (8 elems/thread, 16B loads, 16B stores)
// ---------------------------------------------------------------------------
__global__ __launch_bounds__(256)
void cvt_bf16(const float* __restrict__ in, __hip_bfloat16* __restrict__ out)
{
    int i = blockIdx.x * 256 + threadIdx.x;
    const float4* p = (const float4*)in + (size_t)i * 2;
    float4 a = p[0], b = p[1];
    __hip_bfloat16 t[8];
    t[0]=__float2bfloat16(a.x); t[1]=__float2bfloat16(a.y);
    t[2]=__float2bfloat16(a.z); t[3]=__float2bfloat16(a.w);
    t[4]=__float2bfloat16(b.x); t[5]=__float2bfloat16(b.y);
    t[6]=__float2bfloat16(b.z); t[7]=__float2bfloat16(b.w);
    *(uint4*)(out + (size_t)i * 8) = *(uint4*)t;
}

// ---------------------------------------------------------------------------
// fp32 [K][N] -> bf16 [N][K] transpose-convert, 32x32 LDS tiles
// ---------------------------------------------------------------------------
__global__ __launch_bounds__(256)
void cvt_T(const float* __restrict__ in, __hip_bfloat16* __restrict__ out,
           int K, int N)
{
    __shared__ float t[32][33];
    const int n0 = blockIdx.x * 32, k0 = blockIdx.y * 32;
    const int r = threadIdx.x >> 3, c4 = (threadIdx.x & 7) * 4;
    float4 v = *(const float4*)(in + (size_t)(k0 + r) * N + n0 + c4);
    t[r][c4] = v.x; t[r][c4+1] = v.y; t[r][c4+2] = v.z; t[r][c4+3] = v.w;
    __syncthreads();
    __hip_bfloat16 o[4];
    #pragma unroll
    for (int j = 0; j < 4; ++j) o[j] = __float2bfloat16(t[c4 + j][r]);
    *(uint2*)(out + (size_t)(n0 + r) * K + k0 + c4) = *(uint2*)o;
}

// ---------------------------------------------------------------------------
// m97-structure GEMM: C[m][n] = A[m][:] @ Bt[n][:] + bias[n].
// A bf16 [M][K] row-major, Bt bf16 [N][K] row-major (pre-transposed weight).
// 128x128 tile / 256 threads (4 waves 2x2, each 64x64), BK=32,
// global_load_lds width=16 staging (contiguous LDS, no padding).
// MODE 0: scatter bf16 into qkv ws [3][BH][..]: q,k as [BH][S][Dh], V as
//         [BH][Dh][S] (transposed for the attention V-staging).
// MODE 1: fp32 store row-major [M][2048] to d_out.
// ---------------------------------------------------------------------------
template<int MODE>
__global__ __launch_bounds__(256)
void gemm_bt(const __hip_bfloat16* __restrict__ A,
             const __hip_bfloat16* __restrict__ Bt,
             const float* __restrict__ bias,
             void* __restrict__ outp, int K)
{
    __shared__ __hip_bfloat16 As[128 * 32];   // [m][k], contiguous (DMA layout)
    __shared__ __hip_bfloat16 Bs[128 * 32];   // [n][k], contiguous

    const int tid  = threadIdx.x;
    const int wave = tid >> 6, lane = tid & 63;
    const int quad = lane >> 4, l16 = lane & 15;
    const int m0 = blockIdx.y * 128, n0 = blockIdx.x * 128;
    const int wm = (wave >> 1) * 64, wn = (wave & 1) * 64;

    f32x4 acc[4][4] = {};

    for (int k0 = 0; k0 < K; k0 += 32) {
        __syncthreads();   // previous iteration's frag reads done
        // stage A and B tiles: 128 rows x 32 k = 512 chunks of 8 bf16 each
        #pragma unroll
        for (int pass = 0; pass < 2; ++pass) {
            int c = pass * 256 + tid;            // chunk = row*4 + col8
            int row = c >> 2, col8 = (c & 3) * 8;
            // LDS dest: wave-uniform base + lane*16 (HW rule) == chunk*16
            __hip_bfloat16* la = As + (size_t)(pass * 256 + wave * 64) * 8;
            __hip_bfloat16* lb = Bs + (size_t)(pass * 256 + wave * 64) * 8;
            const __hip_bfloat16* ga = A  + (size_t)(m0 + row) * K + k0 + col8;
            const __hip_bfloat16* gb = Bt + (size_t)(n0 + row) * K + k0 + col8;
            __builtin_amdgcn_global_load_lds((g_u32*)ga, (lds_u32*)la, 16, 0, 0);
            __builtin_amdgcn_global_load_lds((g_u32*)gb, (lds_u32*)lb, 16, 0, 0);
        }
        __syncthreads();   // vmcnt(0) drain inserted by compiler

        bf16x8 af[4], bf[4];
        #pragma unroll
        for (int i = 0; i < 4; ++i)
            af[i] = *(const bf16x8*)(&As[(wm + i * 16 + l16) * 32 + quad * 8]);
        #pragma unroll
        for (int j = 0; j < 4; ++j)
            bf[j] = *(const bf16x8*)(&Bs[(wn + j * 16 + l16) * 32 + quad * 8]);
        #pragma unroll
        for (int i = 0; i < 4; ++i)
            #pragma unroll
            for (int j = 0; j < 4; ++j)
                acc[i][j] = MFMA16(af[i], bf[j], acc[i][j]);
    }

    // epilogue: D row = quad*4+r, col = l16 (verified m89/m91 layout)
    #pragma unroll
    for (int i = 0; i < 4; ++i)
        #pragma unroll
        for (int j = 0; j < 4; ++j) {
            int col = n0 + wn + j * 16 + l16;
            float bs = bias[col];
            #pragma unroll
            for (int r = 0; r < 4; ++r) {
                int row = m0 + wm + i * 16 + quad * 4 + r;
                float v = acc[i][j][r] + bs;
                if (MODE == 0) {
                    int which = col >> 11, h = (col >> 7) & 15, d = col & 127;
                    int bb = row >> 11, s = row & 2047;
                    __hip_bfloat16* o = (__hip_bfloat16*)outp;
                    size_t idx;
                    if (which == 2)   // V transposed: [BH][Dh][S]
                        idx = 2 * (size_t)BH * SEQ * DH +
                              ((size_t)(bb * NH + h) * DH + d) * SEQ + s;
                    else
                        idx = (size_t)which * BH * SEQ * DH +
                              ((size_t)(bb * NH + h) * SEQ + s) * DH + d;
                    o[idx] = __float2bfloat16(v);
                } else {
                    ((float*)outp)[(size_t)row * DM + col] = v;
                }
            }
        }
}

// ---------------------------------------------------------------------------
// Causal flash attention.  Q,K bf16 [BH][S][Dh]; V bf16 [BH][Dh][S] (pre-
// transposed).  One block per (q-tile 64, bh).  4 waves x 16 q rows.
// O written bf16 into [B][S][D_MODEL] for the out-proj GEMM.
// ---------------------------------------------------------------------------
__global__ __launch_bounds__(256)
void attn_kernel(const __hip_bfloat16* __restrict__ q,
                 const __hip_bfloat16* __restrict__ k,
                 const __hip_bfloat16* __restrict__ v,
                 __hip_bfloat16* __restrict__ o)
{
    __shared__ __hip_bfloat16 Qs[64 * 136];   // [qrow][d]  (+8 pad)
    __shared__ __hip_bfloat16 Ks[64 * 136];   // [krow][d]
    __shared__ __hip_bfloat16 Vt[128 * 72];   // [d][krow]  (+8 pad)
    __shared__ __hip_bfloat16 Ps[64 * 72];    // [qrow][krow]

    const int tid  = threadIdx.x;
    const int wave = tid >> 6, lane = tid & 63;
    const int quad = lane >> 4, l16 = lane & 15;
    const int qt = blockIdx.x, bh = blockIdx.y;
    const int q0 = qt * 64;
    const size_t base = (size_t)bh * SEQ * DH;   // same elem count for V^T
    const float scale = 0.08838834764831845f;    // 1/sqrt(128)

    #pragma unroll
    for (int it = 0; it < 4; ++it) {
        int e = it * 2048 + tid * 8;
        int row = e >> 7, col = e & 127;
        *(uint4*)(&Qs[row * 136 + col]) =
            *(const uint4*)(q + base + (size_t)(q0 + row) * DH + col);
    }

    float m_run[4], l_run[4];
    f32x4 oacc[8] = {};
    #pragma unroll
    for (int r = 0; r < 4; ++r) { m_run[r] = -1e30f; l_run[r] = 0.f; }

    for (int kt = 0; kt <= qt; ++kt) {
        __syncthreads();   // prior readers of Ks/Vt done (also covers Qs stage)
        #pragma unroll
        for (int it = 0; it < 4; ++it) {
            int e = it * 2048 + tid * 8;
            int row = e >> 7, col = e & 127;
            *(uint4*)(&Ks[row * 136 + col]) =
                *(const uint4*)(k + base + (size_t)(kt * 64 + row) * DH + col);
            int d = e >> 6, s8 = e & 63;         // V^T: vector stage, no scatter
            *(uint4*)(&Vt[d * 72 + s8]) =
                *(const uint4*)(v + base + (size_t)d * SEQ + kt * 64 + s8);
        }
        __syncthreads();

        // S = Q K^T for this wave's 16 q rows x 64 k cols
        f32x4 sacc[4] = {};
        const int arow = wave * 16 + l16;
        #pragma unroll
        for (int kk = 0; kk < 4; ++kk) {
            bf16x8 a = *(const bf16x8*)(&Qs[arow * 136 + kk * 32 + quad * 8]);
            #pragma unroll
            for (int f = 0; f < 4; ++f) {
                bf16x8 b = *(const bf16x8*)(&Ks[(f * 16 + l16) * 136 + kk * 32 + quad * 8]);
                sacc[f] = MFMA16(a, b, sacc[f]);
            }
        }

        // scale + causal mask + online softmax (rows = quad*4+r)
        const int qrow = q0 + wave * 16 + quad * 4;
        float mloc[4] = {-1e30f, -1e30f, -1e30f, -1e30f};
        #pragma unroll
        for (int f = 0; f < 4; ++f)
            #pragma unroll
            for (int r = 0; r < 4; ++r) {
                float s = sacc[f][r] * scale;
                int kg = kt * 64 + f * 16 + l16;
                if (kg > qrow + r) s = -1e30f;
                sacc[f][r] = s;
                mloc[r] = fmaxf(mloc[r], s);
            }
        #pragma unroll
        for (int off = 1; off < 16; off <<= 1)
            #pragma unroll
            for (int r = 0; r < 4; ++r)
                mloc[r] = fmaxf(mloc[r], __shfl_xor(mloc[r], off, 64));

        float alpha[4], lloc[4] = {0.f, 0.f, 0.f, 0.f};
        #pragma unroll
        for (int r = 0; r < 4; ++r) {
            float mn = fmaxf(m_run[r], mloc[r]);
            alpha[r] = __expf(m_run[r] - mn);
            m_run[r] = mn;
        }
        float pv[4][4];
        #pragma unroll
        for (int f = 0; f < 4; ++f)
            #pragma unroll
            for (int r = 0; r < 4; ++r) {
                float pe = __expf(sacc[f][r] - m_run[r]);
                pv[f][r] = pe;
                lloc[r] += pe;
            }
        #pragma unroll
        for (int off = 1; off < 16; off <<= 1)
            #pragma unroll
            for (int r = 0; r < 4; ++r)
                lloc[r] += __shfl_xor(lloc[r], off, 64);
        #pragma unroll
        for (int r = 0; r < 4; ++r) l_run[r] = l_run[r] * alpha[r] + lloc[r];
        #pragma unroll
        for (int dt = 0; dt < 8; ++dt)
            #pragma unroll
            for (int r = 0; r < 4; ++r) oacc[dt][r] *= alpha[r];

        // P (C-layout) -> LDS -> A-layout (verified m120 round-trip)
        #pragma unroll
        for (int f = 0; f < 4; ++f)
            #pragma unroll
            for (int r = 0; r < 4; ++r)
                Ps[(wave * 16 + quad * 4 + r) * 72 + f * 16 + l16] =
                    __float2bfloat16(pv[f][r]);
        __syncthreads();

        // O += P V : P is A (16 x 64), V is B (64 x 128) via Vt[d][s]
        #pragma unroll
        for (int f2 = 0; f2 < 2; ++f2) {
            bf16x8 a = *(const bf16x8*)(&Ps[(wave * 16 + l16) * 72 + f2 * 32 + quad * 8]);
            #pragma unroll
            for (int dt = 0; dt < 8; ++dt) {
                bf16x8 b = *(const bf16x8*)(&Vt[(dt * 16 + l16) * 72 + f2 * 32 + quad * 8]);
                oacc[dt] = MFMA16(a, b, oacc[dt]);
            }
        }
    }

    // epilogue: normalize and store O (bf16) into [B][S][D_MODEL]
    const int bb = bh >> 4, h = bh & 15;
    #pragma unroll
    for (int dt = 0; dt < 8; ++dt)
        #pragma unroll
        for (int r = 0; r < 4; ++r) {
            int srow = q0 + wave * 16 + quad * 4 + r;
            float val = oacc[dt][r] / l_run[r];
            o[((size_t)(bb * SEQ + srow)) * DM + h * DH + dt * 16 + l16] =
                __float2bfloat16(val);
        }
}

// ---------------------------------------------------------------------------
extern "C" void kernel_launch(void* const* d_in, const int* in_sizes, int n_in,
                              void* d_out, int out_size, void* d_ws, size_t ws_size,
                              hipStream_t stream)
{
    const float* x     = (const float*)d_in[0];   // [4,2048,2048] fp32
    const float* w_qkv = (const float*)d_in[1];   // [2048,6144]   fp32
    const float* b_qkv = (const float*)d_in[2];   // [6144]        fp32
    const float* w_out = (const float*)d_in[3];   // [2048,2048]   fp32
    const float* b_out = (const float*)d_in[4];   // [2048]        fp32
    float* out = (float*)d_out;                   // [4,2048,2048] fp32
    __hip_bfloat16* ws = (__hip_bfloat16*)d_ws;

    constexpr size_t NX    = (size_t)MROWS * DM;        // 16.78M
    constexpr size_t NWQKV = (size_t)DM * 3 * DM;       // 12.58M
    constexpr size_t NWOUT = (size_t)DM * DM;           //  4.19M
    constexpr size_t T     = (size_t)BH * SEQ * DH;     // 16.78M

    __hip_bfloat16* xb    = ws;                         // reused as op later
    __hip_bfloat16* wqkvT = ws + NX;
    __hip_bfloat16* woutT = ws + NX + NWQKV;
    __hip_bfloat16* qkv   = ws + NX + NWQKV + NWOUT;    // q | k | v^T
    __hip_bfloat16* op    = xb;                         // [B][S][D] bf16

    // 0) precision/layout prep (memory-bound, ~35 us total)
    cvt_bf16<<<NX / (8 * 256), 256, 0, stream>>>(x, xb);
    cvt_T<<<dim3(3 * DM / 32, DM / 32), 256, 0, stream>>>(w_qkv, wqkvT, DM, 3 * DM);
    cvt_T<<<dim3(DM / 32, DM / 32), 256, 0, stream>>>(w_out, woutT, DM, DM);

    // 1) fused QKV projection -> q,k [BH][S][Dh], v [BH][Dh][S]
    gemm_bt<0><<<dim3(3 * DM / 128, MROWS / 128), 256, 0, stream>>>(
        xb, wqkvT, b_qkv, qkv, DM);
    // 2) causal flash attention
    attn_kernel<<<dim3(SEQ / 64, BH), 256, 0, stream>>>(
        qkv, qkv + T, qkv + 2 * T, op);
    // 3) output projection -> fp32 d_out
    gemm_bt<1><<<dim3(DM / 128, MROWS / 128), 256, 0, stream>>>(
        op, woutT, b_out, out, DM);
}

// Round 4
// 870.256 us; speedup vs baseline: 2.4593x; 1.0796x over previous
//
#include <hip/hip_runtime.h>
#include <hip/hip_bf16.h>

typedef short bf16x8 __attribute__((ext_vector_type(8)));   // 8 bf16 in 4 VGPRs
typedef float f32x4  __attribute__((ext_vector_type(4)));   // MFMA C/D frag

#define MFMA16(a,b,c) __builtin_amdgcn_mfma_f32_16x16x32_bf16((a),(b),(c),0,0,0)

typedef __attribute__((address_space(3))) unsigned int       lds_u32;
typedef const __attribute__((address_space(1))) unsigned int g_u32;

static constexpr int SEQ = 2048;
static constexpr int DM  = 2048;
static constexpr int NH  = 16;
static constexpr int DH  = 128;
static constexpr int BAT = 4;
static constexpr int BH  = BAT * NH;      // 64
static constexpr int MROWS = BAT * SEQ;   // 8192

// ---------------------------------------------------------------------------
// fp32 -> bf16 elementwise (8 elems/thread, 16B loads, 16B stores)
// ---------------------------------------------------------------------------
__global__ __launch_bounds__(256)
void cvt_bf16(const float* __restrict__ in, __hip_bfloat16* __restrict__ out)
{
    int i = blockIdx.x * 256 + threadIdx.x;
    const float4* p = (const float4*)in + (size_t)i * 2;
    float4 a = p[0], b = p[1];
    __hip_bfloat16 t[8];
    t[0]=__float2bfloat16(a.x); t[1]=__float2bfloat16(a.y);
    t[2]=__float2bfloat16(a.z); t[3]=__float2bfloat16(a.w);
    t[4]=__float2bfloat16(b.x); t[5]=__float2bfloat16(b.y);
    t[6]=__float2bfloat16(b.z); t[7]=__float2bfloat16(b.w);
    *(uint4*)(out + (size_t)i * 8) = *(uint4*)t;
}

// ---------------------------------------------------------------------------
// fp32 [K][N] -> bf16 [N][K] transpose-convert, 32x32 LDS tiles
// ---------------------------------------------------------------------------
__global__ __launch_bounds__(256)
void cvt_T(const float* __restrict__ in, __hip_bfloat16* __restrict__ out,
           int K, int N)
{
    __shared__ float t[32][33];
    const int n0 = blockIdx.x * 32, k0 = blockIdx.y * 32;
    const int r = threadIdx.x >> 3, c4 = (threadIdx.x & 7) * 4;
    float4 v = *(const float4*)(in + (size_t)(k0 + r) * N + n0 + c4);
    t[r][c4] = v.x; t[r][c4+1] = v.y; t[r][c4+2] = v.z; t[r][c4+3] = v.w;
    __syncthreads();
    __hip_bfloat16 o[4];
    #pragma unroll
    for (int j = 0; j < 4; ++j) o[j] = __float2bfloat16(t[c4 + j][r]);
    *(uint2*)(out + (size_t)(n0 + r) * K + k0 + c4) = *(uint2*)o;
}

// ---------------------------------------------------------------------------
// m97-structure GEMM: C[m][n] = A[m][:] @ Bt[n][:] + bias[n].
// A bf16 [M][K] row-major, Bt bf16 [N][K] row-major (pre-transposed weight).
// 128x128 tile / 256 threads (4 waves 2x2, each 64x64), BK=32,
// global_load_lds width=16 staging (contiguous LDS, no padding).
// MODE 0: scatter bf16 into qkv ws [3][BH][..]: q,k as [BH][S][Dh], V as
//         [BH][Dh][S] (transposed for the attention V-staging).
// MODE 1: fp32 store row-major [M][2048] to d_out.
// ---------------------------------------------------------------------------
template<int MODE>
__global__ __launch_bounds__(256)
void gemm_bt(const __hip_bfloat16* __restrict__ A,
             const __hip_bfloat16* __restrict__ Bt,
             const float* __restrict__ bias,
             void* __restrict__ outp, int K)
{
    __shared__ __hip_bfloat16 As[128 * 32];   // [m][k], contiguous (DMA layout)
    __shared__ __hip_bfloat16 Bs[128 * 32];   // [n][k], contiguous

    const int tid  = threadIdx.x;
    const int wave = tid >> 6, lane = tid & 63;
    const int quad = lane >> 4, l16 = lane & 15;
    const int m0 = blockIdx.y * 128, n0 = blockIdx.x * 128;
    const int wm = (wave >> 1) * 64, wn = (wave & 1) * 64;

    f32x4 acc[4][4] = {};

    for (int k0 = 0; k0 < K; k0 += 32) {
        __syncthreads();   // previous iteration's frag reads done
        #pragma unroll
        for (int pass = 0; pass < 2; ++pass) {
            int c = pass * 256 + tid;            // chunk = row*4 + col8
            int row = c >> 2, col8 = (c & 3) * 8;
            __hip_bfloat16* la = As + (size_t)(pass * 256 + wave * 64) * 8;
            __hip_bfloat16* lb = Bs + (size_t)(pass * 256 + wave * 64) * 8;
            const __hip_bfloat16* ga = A  + (size_t)(m0 + row) * K + k0 + col8;
            const __hip_bfloat16* gb = Bt + (size_t)(n0 + row) * K + k0 + col8;
            __builtin_amdgcn_global_load_lds((g_u32*)ga, (lds_u32*)la, 16, 0, 0);
            __builtin_amdgcn_global_load_lds((g_u32*)gb, (lds_u32*)lb, 16, 0, 0);
        }
        __syncthreads();   // vmcnt(0) drain inserted by compiler

        bf16x8 af[4], bf[4];
        #pragma unroll
        for (int i = 0; i < 4; ++i)
            af[i] = *(const bf16x8*)(&As[(wm + i * 16 + l16) * 32 + quad * 8]);
        #pragma unroll
        for (int j = 0; j < 4; ++j)
            bf[j] = *(const bf16x8*)(&Bs[(wn + j * 16 + l16) * 32 + quad * 8]);
        #pragma unroll
        for (int i = 0; i < 4; ++i)
            #pragma unroll
            for (int j = 0; j < 4; ++j)
                acc[i][j] = MFMA16(af[i], bf[j], acc[i][j]);
    }

    // epilogue: D row = quad*4+r, col = l16 (verified m89/m91 layout)
    #pragma unroll
    for (int i = 0; i < 4; ++i)
        #pragma unroll
        for (int j = 0; j < 4; ++j) {
            int col = n0 + wn + j * 16 + l16;
            float bs = bias[col];
            #pragma unroll
            for (int r = 0; r < 4; ++r) {
                int row = m0 + wm + i * 16 + quad * 4 + r;
                float v = acc[i][j][r] + bs;
                if (MODE == 0) {
                    int which = col >> 11, h = (col >> 7) & 15, d = col & 127;
                    int bb = row >> 11, s = row & 2047;
                    __hip_bfloat16* o = (__hip_bfloat16*)outp;
                    size_t idx;
                    if (which == 2)   // V transposed: [BH][Dh][S]
                        idx = 2 * (size_t)BH * SEQ * DH +
                              ((size_t)(bb * NH + h) * DH + d) * SEQ + s;
                    else
                        idx = (size_t)which * BH * SEQ * DH +
                              ((size_t)(bb * NH + h) * SEQ + s) * DH + d;
                    o[idx] = __float2bfloat16(v);
                } else {
                    ((float*)outp)[(size_t)row * DM + col] = v;
                }
            }
        }
}

// ---------------------------------------------------------------------------
// Causal flash attention.  Q,K bf16 [BH][S][Dh]; V bf16 [BH][Dh][S] (pre-
// transposed).  One block per (q-tile 64, bh), 4 waves x 16 q rows.
// LDS 32 KB total -> 4 blocks/CU.  K and V staged via global_load_lds into
// GEMM-style slabs [kk][64][32] / [f2][128][32] (2-way bank aliasing = free).
// P-matrix LDS aliases the K region (one extra barrier guards the overwrite;
// Ps rows are wave-private so no barrier before the PV reads).
// ---------------------------------------------------------------------------
__global__ __launch_bounds__(256, 4)
void attn_kernel(const __hip_bfloat16* __restrict__ q,
                 const __hip_bfloat16* __restrict__ k,
                 const __hip_bfloat16* __restrict__ v,
                 __hip_bfloat16* __restrict__ o)
{
    __shared__ __hip_bfloat16 KP[4 * 64 * 32];    // 16 KB: Ks slabs / Ps alias
    __shared__ __hip_bfloat16 Vs[2 * 128 * 32];   // 16 KB: [f2][d][s8]

    const int tid  = threadIdx.x;
    const int wave = tid >> 6, lane = tid & 63;
    const int quad = lane >> 4, l16 = lane & 15;
    const int qt = gridDim.x - 1 - blockIdx.x;    // heavy causal tiles first
    const int bh = blockIdx.y;
    const int q0 = qt * 64;
    const size_t base = (size_t)bh * SEQ * DH;    // same elem count for V^T
    const float scale = 0.08838834764831845f;     // 1/sqrt(128)

    // Q fragments in registers, prescaled: A[m=l16][k=quad*8+j]
    bf16x8 qf[4];
    #pragma unroll
    for (int kk = 0; kk < 4; ++kk) {
        bf16x8 raw = *(const bf16x8*)(
            q + base + (size_t)(q0 + wave * 16 + l16) * DH + kk * 32 + quad * 8);
        #pragma unroll
        for (int j = 0; j < 8; ++j) {
            __hip_bfloat16 h = ((const __hip_bfloat16*)&raw)[j];
            ((__hip_bfloat16*)&qf[kk])[j] =
                __float2bfloat16(__bfloat162float(h) * scale);
        }
    }

    float m_run[4], l_run[4];
    f32x4 oacc[8] = {};
    #pragma unroll
    for (int r = 0; r < 4; ++r) { m_run[r] = -1e30f; l_run[r] = 0.f; }

    for (int kt = 0; kt <= qt; ++kt) {
        __syncthreads();   // prior iter's Ps(=KP) and Vs reads done
        // ---- DMA-stage K tile (4 slabs [64][32]) and V^T tile (2 slabs) ----
        const __hip_bfloat16* kbase = k + base + (size_t)(kt * 64) * DH;
        const __hip_bfloat16* vbase = v + base + kt * 64;
        #pragma unroll
        for (int p = 0; p < 4; ++p) {
            int c = p * 256 + tid;                     // chunk id = LDS/16B
            int kk = c >> 8, krow = (c >> 2) & 63, h = c & 3;
            const __hip_bfloat16* gk = kbase + (size_t)krow * DH + kk * 32 + h * 8;
            __hip_bfloat16* lk = KP + (size_t)(p * 256 + wave * 64) * 8;
            __builtin_amdgcn_global_load_lds((g_u32*)gk, (lds_u32*)lk, 16, 0, 0);
            int f2 = c >> 9, d = (c >> 2) & 127;
            const __hip_bfloat16* gv = vbase + (size_t)d * SEQ + f2 * 32 + h * 8;
            __hip_bfloat16* lv = Vs + (size_t)(p * 256 + wave * 64) * 8;
            __builtin_amdgcn_global_load_lds((g_u32*)gv, (lds_u32*)lv, 16, 0, 0);
        }
        __syncthreads();   // staging visible (vmcnt drain + barrier)

        // ---- S = (Q*scale) K^T : 16 q rows x 64 k cols per wave ----
        f32x4 sacc[4] = {};
        #pragma unroll
        for (int kk = 0; kk < 4; ++kk)
            #pragma unroll
            for (int f = 0; f < 4; ++f) {
                bf16x8 b = *(const bf16x8*)(
                    &KP[kk * 2048 + (f * 16 + l16) * 32 + quad * 8]);
                sacc[f] = MFMA16(qf[kk], b, sacc[f]);
            }

        // ---- causal mask + online softmax (rows = quad*4+r) ----
        const int qrow = q0 + wave * 16 + quad * 4;
        float mloc[4] = {-1e30f, -1e30f, -1e30f, -1e30f};
        #pragma unroll
        for (int f = 0; f < 4; ++f)
            #pragma unroll
            for (int r = 0; r < 4; ++r) {
                float s = sacc[f][r];
                int kg = kt * 64 + f * 16 + l16;
                if (kg > qrow + r) s = -1e30f;
                sacc[f][r] = s;
                mloc[r] = fmaxf(mloc[r], s);
            }
        #pragma unroll
        for (int off = 1; off < 16; off <<= 1)
            #pragma unroll
            for (int r = 0; r < 4; ++r)
                mloc[r] = fmaxf(mloc[r], __shfl_xor(mloc[r], off, 64));

        float alpha[4], lloc[4] = {0.f, 0.f, 0.f, 0.f};
        #pragma unroll
        for (int r = 0; r < 4; ++r) {
            float mn = fmaxf(m_run[r], mloc[r]);
            alpha[r] = __expf(m_run[r] - mn);
            m_run[r] = mn;
        }
        float pv[4][4];
        #pragma unroll
        for (int f = 0; f < 4; ++f)
            #pragma unroll
            for (int r = 0; r < 4; ++r) {
                float pe = __expf(sacc[f][r] - m_run[r]);
                pv[f][r] = pe;
                lloc[r] += pe;
            }
        #pragma unroll
        for (int off = 1; off < 16; off <<= 1)
            #pragma unroll
            for (int r = 0; r < 4; ++r)
                lloc[r] += __shfl_xor(lloc[r], off, 64);
        #pragma unroll
        for (int r = 0; r < 4; ++r) l_run[r] = l_run[r] * alpha[r] + lloc[r];
        #pragma unroll
        for (int dt = 0; dt < 8; ++dt)
            #pragma unroll
            for (int r = 0; r < 4; ++r) oacc[dt][r] *= alpha[r];

        // ---- P (C-layout) -> LDS (aliases Ks) -> A-layout ----
        __syncthreads();   // ALL waves done reading Ks before overwrite
        #pragma unroll
        for (int f = 0; f < 4; ++f)
            #pragma unroll
            for (int r = 0; r < 4; ++r)
                KP[(wave * 16 + quad * 4 + r) * 72 + f * 16 + l16] =
                    __float2bfloat16(pv[f][r]);
        // Ps rows are wave-private: same-wave RAW covered by lgkmcnt, no barrier

        // ---- O += P V ----
        #pragma unroll
        for (int f2 = 0; f2 < 2; ++f2) {
            bf16x8 a = *(const bf16x8*)(
                &KP[(wave * 16 + l16) * 72 + f2 * 32 + quad * 8]);
            #pragma unroll
            for (int dt = 0; dt < 8; ++dt) {
                bf16x8 b = *(const bf16x8*)(
                    &Vs[f2 * 4096 + (dt * 16 + l16) * 32 + quad * 8]);
                oacc[dt] = MFMA16(a, b, oacc[dt]);
            }
        }
    }

    // epilogue: normalize and store O (bf16) into [B][S][D_MODEL]
    const int bb = bh >> 4, h = bh & 15;
    #pragma unroll
    for (int dt = 0; dt < 8; ++dt)
        #pragma unroll
        for (int r = 0; r < 4; ++r) {
            int srow = q0 + wave * 16 + quad * 4 + r;
            float val = oacc[dt][r] / l_run[r];
            o[((size_t)(bb * SEQ + srow)) * DM + h * DH + dt * 16 + l16] =
                __float2bfloat16(val);
        }
}

// ---------------------------------------------------------------------------
extern "C" void kernel_launch(void* const* d_in, const int* in_sizes, int n_in,
                              void* d_out, int out_size, void* d_ws, size_t ws_size,
                              hipStream_t stream)
{
    const float* x     = (const float*)d_in[0];   // [4,2048,2048] fp32
    const float* w_qkv = (const float*)d_in[1];   // [2048,6144]   fp32
    const float* b_qkv = (const float*)d_in[2];   // [6144]        fp32
    const float* w_out = (const float*)d_in[3];   // [2048,2048]   fp32
    const float* b_out = (const float*)d_in[4];   // [2048]        fp32
    float* out = (float*)d_out;                   // [4,2048,2048] fp32
    __hip_bfloat16* ws = (__hip_bfloat16*)d_ws;

    constexpr size_t NX    = (size_t)MROWS * DM;        // 16.78M
    constexpr size_t NWQKV = (size_t)DM * 3 * DM;       // 12.58M
    constexpr size_t NWOUT = (size_t)DM * DM;           //  4.19M
    constexpr size_t T     = (size_t)BH * SEQ * DH;     // 16.78M

    __hip_bfloat16* xb    = ws;                         // reused as op later
    __hip_bfloat16* wqkvT = ws + NX;
    __hip_bfloat16* woutT = ws + NX + NWQKV;
    __hip_bfloat16* qkv   = ws + NX + NWQKV + NWOUT;    // q | k | v^T
    __hip_bfloat16* op    = xb;                         // [B][S][D] bf16

    // 0) precision/layout prep (memory-bound, ~35 us total)
    cvt_bf16<<<NX / (8 * 256), 256, 0, stream>>>(x, xb);
    cvt_T<<<dim3(3 * DM / 32, DM / 32), 256, 0, stream>>>(w_qkv, wqkvT, DM, 3 * DM);
    cvt_T<<<dim3(DM / 32, DM / 32), 256, 0, stream>>>(w_out, woutT, DM, DM);

    // 1) fused QKV projection -> q,k [BH][S][Dh], v [BH][Dh][S]
    gemm_bt<0><<<dim3(3 * DM / 128, MROWS / 128), 256, 0, stream>>>(
        xb, wqkvT, b_qkv, qkv, DM);
    // 2) causal flash attention
    attn_kernel<<<dim3(SEQ / 64, BH), 256, 0, stream>>>(
        qkv, qkv + T, qkv + 2 * T, op);
    // 3) output projection -> fp32 d_out
    gemm_bt<1><<<dim3(DM / 128, MROWS / 128), 256, 0, stream>>>(
        op, woutT, b_out, out, DM);
}